// Round 2
// baseline (305.917 us; speedup 1.0000x reference)
//
#include <hip/hip_runtime.h>

#define NB    384            // 6 waves; 1152 = 384*3
#define ROWS  3
#define N_ROUTE 1152
#define C_IN  8
#define C_OUT 16

// P fully register-resident: 3 rows x 16 = 48 VGPRs/thread. No LDS on the
// critical path; LDS only holds 17-float cross-wave reduction scratch.
// launch_bounds(384,4): cap VGPR at 128 -> 2 blocks/CU = 12 waves/CU.
__global__ __launch_bounds__(NB, 4)
void capsule_routing(const float* __restrict__ x,
                     const float* __restrict__ W,
                     float* __restrict__ out)
{
    // double-buffered reduction scratch: [buf][wave][16 s-partials + Z], padded to 20
    __shared__ float red[2][6][20];

    const int t    = threadIdx.x;
    const int bid  = blockIdx.x;
    const int c    = bid >> 8;
    const int b    = bid & 255;
    const int lane = t & 63;
    const int wid  = t >> 6;

    float p[ROWS][16];   // priors for owned rows n = t + 384k  (static idx only)

    // ---------------- Phase A: priors, fully per-thread ----------------
    {
        const float* __restrict__ xb = x + (size_t)b * (N_ROUTE * C_IN);
        const float* __restrict__ Wc = W + (size_t)c * (N_ROUTE * C_IN * C_OUT);
        #pragma unroll
        for (int k = 0; k < ROWS; ++k) {
            const int n = t + k * NB;
            const float4 x0 = *reinterpret_cast<const float4*>(xb + n * C_IN);
            const float4 x1 = *reinterpret_cast<const float4*>(xb + n * C_IN + 4);
            const float xs[8] = {x0.x, x0.y, x0.z, x0.w, x1.x, x1.y, x1.z, x1.w};
            const float4* __restrict__ wp =
                reinterpret_cast<const float4*>(Wc + (size_t)n * (C_IN * C_OUT));
            #pragma unroll
            for (int o = 0; o < 16; ++o) p[k][o] = 0.f;
            #pragma unroll
            for (int i = 0; i < 8; ++i) {
                const float xi = xs[i];
                #pragma unroll
                for (int q = 0; q < 4; ++q) {
                    const float4 w = wp[i * 4 + q];
                    p[k][q * 4 + 0] = fmaf(xi, w.x, p[k][q * 4 + 0]);
                    p[k][q * 4 + 1] = fmaf(xi, w.y, p[k][q * 4 + 1]);
                    p[k][q * 4 + 2] = fmaf(xi, w.z, p[k][q * 4 + 2]);
                    p[k][q * 4 + 3] = fmaf(xi, w.w, p[k][q * 4 + 3]);
                }
            }
        }
    }
    // No barrier needed: each thread computed its own P rows.

    float lg[ROWS] = {0.f, 0.f, 0.f};
    float vcur[16];

    #pragma unroll
    for (int it = 0; it < 3; ++it) {
        // e[n] = exp(logit[n]); no max-subtraction needed:
        // |logit| <= ||P_row|| (Cauchy-Schwarz, ||v||<1) << 88.
        float ek[ROWS];
        float zp;
        if (it == 0) {
            ek[0] = ek[1] = ek[2] = 1.f;
            zp = 3.f;                       // softmax of zeros = uniform
        } else {
            zp = 0.f;
            #pragma unroll
            for (int k = 0; k < ROWS; ++k) { ek[k] = __expf(lg[k]); zp += ek[k]; }
        }

        // per-thread partial s[o] = sum_k e_k * P[k][o]
        float sp[16];
        #pragma unroll
        for (int o = 0; o < 16; ++o) sp[o] = 0.f;
        #pragma unroll
        for (int k = 0; k < ROWS; ++k) {
            const float e = ek[k];
            #pragma unroll
            for (int o = 0; o < 16; ++o) sp[o] = fmaf(e, p[k][o], sp[o]);
        }

        // fused 17-value butterfly reduce (16 s-partials + Z) across the wave
        #pragma unroll
        for (int off = 32; off >= 1; off >>= 1) {
            #pragma unroll
            for (int o = 0; o < 16; ++o) sp[o] += __shfl_xor(sp[o], off);
            zp += __shfl_xor(zp, off);
        }

        float (*rb)[20] = red[it & 1];
        if (lane == 0) {
            #pragma unroll
            for (int o = 0; o < 16; ++o) rb[wid][o] = sp[o];
            rb[wid][16] = zp;
        }
        __syncthreads();                    // the only barrier per iteration

        float s[16];
        #pragma unroll
        for (int o = 0; o < 16; ++o) s[o] = 0.f;
        float Z = 0.f;
        #pragma unroll
        for (int w2 = 0; w2 < 6; ++w2) {    // broadcast reads: conflict-free
            #pragma unroll
            for (int o = 0; o < 16; ++o) s[o] += rb[w2][o];
            Z += rb[w2][16];
        }

        const float Zinv = 1.f / Z;
        float sq = 0.f;
        #pragma unroll
        for (int o = 0; o < 16; ++o) { s[o] *= Zinv; sq = fmaf(s[o], s[o], sq); }
        const float fac = sqrtf(sq) / (1.f + sq);   // squash factor
        #pragma unroll
        for (int o = 0; o < 16; ++o) vcur[o] = s[o] * fac;

        if (it < 2) {
            // logit[n] += dot(P[n], v)   (scalar per n — Co-independent)
            #pragma unroll
            for (int k = 0; k < ROWS; ++k) {
                float d = 0.f;
                #pragma unroll
                for (int o = 0; o < 16; ++o) d = fmaf(p[k][o], vcur[o], d);
                lg[k] += d;
            }
        }
    }

    if (t < 16) out[((size_t)bid << 4) + t] = vcur[t];
}

extern "C" void kernel_launch(void* const* d_in, const int* in_sizes, int n_in,
                              void* d_out, int out_size, void* d_ws, size_t ws_size,
                              hipStream_t stream)
{
    const float* x   = (const float*)d_in[0];
    const float* W   = (const float*)d_in[1];
    float*       out = (float*)d_out;
    capsule_routing<<<dim3(10 * 256), dim3(NB), 0, stream>>>(x, W, out);
}